// Round 10
// baseline (328.268 us; speedup 1.0000x reference)
//
#include <hip/hip_runtime.h>
#include <hip/hip_bf16.h>
#include <cstdint>

#define B_SZ   4096
#define F_SZ   30
#define D_SZ   128
#define P_SZ   435
#define BM     128
#define PCH    15                     // consecutive pairs per block
#define NCHUNK 29                     // 435 / 15
#define FD     (F_SZ * D_SZ)          // 3840
#define FEMB_ELEMS (B_SZ * F_SZ * D_SZ)
#define W_ELEMS    (P_SZ * D_SZ * D_SZ)
#define GRID_MAIN  (NCHUNK * 32)      // 928 = 8 * 116

typedef __bf16 bf16x8 __attribute__((ext_vector_type(8)));
typedef float  f32x4  __attribute__((ext_vector_type(4)));
typedef unsigned short u16x8 __attribute__((ext_vector_type(8)));
typedef unsigned short u16x4 __attribute__((ext_vector_type(4)));

__device__ __forceinline__ unsigned short f2bf(float x) {
    unsigned int u = __float_as_uint(x);
    u += 0x7fffu + ((u >> 16) & 1u);
    return (unsigned short)(u >> 16);
}
__device__ __forceinline__ float bf2f(unsigned short v) {
    return __uint_as_float(((unsigned int)v) << 16);
}
__device__ __forceinline__ void gl_lds16(const void* g, void* l) {
    __builtin_amdgcn_global_load_lds(
        (const __attribute__((address_space(1))) unsigned int*)g,
        (__attribute__((address_space(3))) unsigned int*)l, 16, 0, 0);
}
#define LGKM_BAR() do { \
    asm volatile("s_waitcnt lgkmcnt(0)" ::: "memory"); \
    __builtin_amdgcn_s_barrier(); } while (0)

__global__ __launch_bounds__(256)
void cvt_bf16_kernel(const float* __restrict__ src,
                     unsigned short* __restrict__ dst, int n8) {
    int stride = gridDim.x * blockDim.x;
    for (int i = blockIdx.x * blockDim.x + threadIdx.x; i < n8; i += stride) {
        const float* s = src + (size_t)i * 8;
        f32x4 a = *reinterpret_cast<const f32x4*>(s);
        f32x4 b = *reinterpret_cast<const f32x4*>(s + 4);
        u16x8 v;
        v[0]=f2bf(a[0]); v[1]=f2bf(a[1]); v[2]=f2bf(a[2]); v[3]=f2bf(a[3]);
        v[4]=f2bf(b[0]); v[5]=f2bf(b[1]); v[6]=f2bf(b[2]); v[7]=f2bf(b[3]);
        *reinterpret_cast<u16x8*>(dst + (size_t)i * 8) = v;
    }
}

// block = (b-tile 128 rows, 15 consecutive pairs), 512 thr / 8 waves.
// Epilogue: acc -> LDS scratch (reusing As) -> row-major readback; every
// global store is a 512B-contiguous segment. In-loop barriers lgkm-only.
// R10 A/B: plain (L2-cached) stores instead of NT — stores retire at L2
// latency so the vmcnt queue drains fast; dirty lines stream to HBM async.
__global__ __launch_bounds__(512, 2)
void bilinear_kernel(const unsigned short* __restrict__ wsA,
                     const unsigned short* __restrict__ wsW,
                     float* __restrict__ out) {
    __shared__ unsigned short As[BM * D_SZ];     // 32 KB; scratch after prologue
    __shared__ unsigned short Ws[D_SZ * D_SZ];   // 32 KB
    float* scrf = reinterpret_cast<float*>(As);  // [64 rows][32 chunks16B] swz

    // XCD swizzle: each XCD owns a 4-btile group (vj slice 3.9 MB -> L2-fit)
    const int orig  = blockIdx.x;
    const int btgrp = orig & 7;
    const int idx   = orig >> 3;          // 0..115
    const int chunk = idx % NCHUNK;
    const int btsub = idx / NCHUNK;       // 0..3
    const int m0    = (btgrp * 4 + btsub) * BM;
    const int p0    = chunk * PCH;

    int fi = 0, rem = p0;
    while (rem >= F_SZ - 1 - fi) { rem -= F_SZ - 1 - fi; ++fi; }
    int fj = fi + 1 + rem;

    const int tid  = threadIdx.x;
    const int lane = tid & 63;
    const int wave = tid >> 6;      // 0..7
    const int l16  = lane >> 4;
    const int lc   = lane & 15;

    // ---- prologue: stage A(fi) + W(p0) via global_load_lds, swizzled src ----
    {
        const unsigned short* baseA = wsA + (size_t)m0 * FD + fi * D_SZ;
        #pragma unroll
        for (int it = 0; it < 4; ++it) {
            int r0 = it * 32 + wave * 4;
            int rl = r0 + l16;
            int cs = lc ^ (rl & 7);
            gl_lds16(baseA + (size_t)rl * FD + cs * 8, &As[r0 * 128]);
        }
        const unsigned short* baseW = wsW + (size_t)p0 * (D_SZ * D_SZ);
        #pragma unroll
        for (int it = 0; it < 4; ++it) {
            int r0 = it * 32 + wave * 4;
            int rl = r0 + l16;
            int cs = lc ^ (rl & 7);
            gl_lds16(baseW + rl * 128 + cs * 8, &Ws[r0 * 128]);
        }
    }
    __syncthreads();    // full drain once (gl_lds)

    const int wb = (wave & 3) * 32;    // b-range (32 rows) of this wave
    const int we = (wave >> 2) * 64;   // e-range (64) of this wave
    const int pass_sel = (wave & 3) >> 1;   // which pass this wave's rows are in
    const int rbase    = (wave & 1) * 32;   // row base within the pass region

    bf16x8 afr[2][4];
    #pragma unroll
    for (int m = 0; m < 2; ++m) {
        int bl = wb + m * 16 + lc;
        #pragma unroll
        for (int kk = 0; kk < 4; ++kk)
            afr[m][kk] = *reinterpret_cast<const bf16x8*>(
                &As[bl * 128 + (((kk * 4 + l16) ^ (bl & 7)) * 8)]);
    }

    for (int s = 0;;) {
        const int p = p0 + s;
        const bool has_next = (s + 1 < PCH);   // block-uniform

        int fi_n = fi, fj_n = fj;
        bool achg = false;
        u16x8 wreg[4];
        if (has_next) {
            const bool wrap = (fj == F_SZ - 1);
            fi_n = wrap ? fi + 1 : fi;
            fj_n = wrap ? fi + 2 : fj + 1;
            achg = wrap;
            const unsigned short* baseW = wsW + (size_t)(p + 1) * (D_SZ * D_SZ);
            #pragma unroll
            for (int it = 0; it < 4; ++it)
                wreg[it] = *reinterpret_cast<const u16x8*>(
                    baseW + (it * 512 + tid) * 8);
        }

        // ---- MFMA ----
        f32x4 acc[4][2];
        #pragma unroll
        for (int n = 0; n < 4; ++n)
            #pragma unroll
            for (int m = 0; m < 2; ++m) acc[n][m] = (f32x4)0.0f;

        #pragma unroll
        for (int n = 0; n < 4; ++n) {
            int el = we + n * 16 + lc;
            #pragma unroll
            for (int kk = 0; kk < 4; ++kk) {
                bf16x8 wfr = *reinterpret_cast<const bf16x8*>(
                    &Ws[el * 128 + (((kk * 4 + l16) ^ (el & 7)) * 8)]);
                #pragma unroll
                for (int m = 0; m < 2; ++m)
                    acc[n][m] = __builtin_amdgcn_mfma_f32_16x16x32_bf16(
                        wfr, afr[m][kk], acc[n][m], 0, 0, 0);
            }
        }

        LGKM_BAR();   // MFMA Ws/scr reads done everywhere

        // ---- phase B: restage next W; pass-0 waves dump acc to scratch ----
        if (has_next) {
            #pragma unroll
            for (int it = 0; it < 4; ++it) {
                int cl  = it * 512 + tid;
                int row = cl >> 4;
                int c   = cl & 15;
                *reinterpret_cast<u16x8*>(
                    &Ws[row * 128 + ((c ^ (row & 7)) * 8)]) = wreg[it];
            }
        }
        if (pass_sel == 0) {
            #pragma unroll
            for (int m = 0; m < 2; ++m) {
                int r = rbase + m * 16 + lc;
                #pragma unroll
                for (int n = 0; n < 4; ++n) {
                    int c = (we >> 2) + n * 4 + l16;
                    *reinterpret_cast<f32x4*>(
                        &scrf[(r * 32 + (c ^ (r & 7))) * 4]) = acc[n][m];
                }
            }
        }
        LGKM_BAR();

        // ---- phase C: readback pass 0 (rows m0..m0+63), contiguous stores --
        #pragma unroll
        for (int i = 0; i < 4; ++i) {
            int fb = i * 8192 + tid * 16;      // byte in 32KB pass region
            int r  = fb >> 9;                  // row 0..63
            int cb = (fb >> 4) & 31;           // 16B chunk in row
            f32x4 v = *reinterpret_cast<const f32x4*>(
                &scrf[(r * 32 + (cb ^ (r & 7))) * 4]);
            int bg = m0 + r;
            u16x4 vjb = *reinterpret_cast<const u16x4*>(
                wsA + (size_t)bg * FD + fj * D_SZ + cb * 4);
            f32x4 o;
            o[0] = v[0] * bf2f(vjb[0]);
            o[1] = v[1] * bf2f(vjb[1]);
            o[2] = v[2] * bf2f(vjb[2]);
            o[3] = v[3] * bf2f(vjb[3]);
            *reinterpret_cast<f32x4*>(
                out + ((size_t)bg * P_SZ + p) * D_SZ + cb * 4) = o;
        }
        LGKM_BAR();

        // ---- phase D: pass-1 waves dump acc ----
        if (pass_sel == 1) {
            #pragma unroll
            for (int m = 0; m < 2; ++m) {
                int r = rbase + m * 16 + lc;
                #pragma unroll
                for (int n = 0; n < 4; ++n) {
                    int c = (we >> 2) + n * 4 + l16;
                    *reinterpret_cast<f32x4*>(
                        &scrf[(r * 32 + (c ^ (r & 7))) * 4]) = acc[n][m];
                }
            }
        }
        LGKM_BAR();

        // ---- phase E: readback pass 1 (rows m0+64..m0+127) ----
        #pragma unroll
        for (int i = 0; i < 4; ++i) {
            int fb = i * 8192 + tid * 16;
            int r  = fb >> 9;
            int cb = (fb >> 4) & 31;
            f32x4 v = *reinterpret_cast<const f32x4*>(
                &scrf[(r * 32 + (cb ^ (r & 7))) * 4]);
            int bg = m0 + 64 + r;
            u16x4 vjb = *reinterpret_cast<const u16x4*>(
                wsA + (size_t)bg * FD + fj * D_SZ + cb * 4);
            f32x4 o;
            o[0] = v[0] * bf2f(vjb[0]);
            o[1] = v[1] * bf2f(vjb[1]);
            o[2] = v[2] * bf2f(vjb[2]);
            o[3] = v[3] * bf2f(vjb[3]);
            *reinterpret_cast<f32x4*>(
                out + ((size_t)bg * P_SZ + p) * D_SZ + cb * 4) = o;
        }

        if (!has_next) break;

        // ---- A-fragment reload straight from global on fi change ----
        if (achg) {
            #pragma unroll
            for (int m = 0; m < 2; ++m) {
                const unsigned short* ar =
                    wsA + (size_t)(m0 + wb + m * 16 + lc) * FD + fi_n * D_SZ;
                #pragma unroll
                for (int kk = 0; kk < 4; ++kk)
                    afr[m][kk] = *reinterpret_cast<const bf16x8*>(
                        ar + (kk * 4 + l16) * 8);
            }
        }
        fi = fi_n; fj = fj_n; ++s;
    }
}

extern "C" void kernel_launch(void* const* d_in, const int* in_sizes, int n_in,
                              void* d_out, int out_size, void* d_ws, size_t ws_size,
                              hipStream_t stream) {
    const float* femb = (const float*)d_in[0];
    const float* W    = (const float*)d_in[1];
    float* out        = (float*)d_out;

    unsigned short* wsA = (unsigned short*)d_ws;
    unsigned short* wsW = wsA + FEMB_ELEMS;

    hipLaunchKernelGGL(cvt_bf16_kernel, dim3(2048), dim3(256), 0, stream,
                       femb, wsA, FEMB_ELEMS / 8);
    hipLaunchKernelGGL(cvt_bf16_kernel, dim3(2048), dim3(256), 0, stream,
                       W, wsW, W_ELEMS / 8);
    hipLaunchKernelGGL(bilinear_kernel, dim3(GRID_MAIN), dim3(512), 0, stream,
                       wsA, wsW, out);
}

// Round 11
// 248.209 us; speedup vs baseline: 1.3225x; 1.3225x over previous
//
#include <hip/hip_runtime.h>
#include <hip/hip_bf16.h>
#include <cstdint>

#define B_SZ   4096
#define F_SZ   30
#define D_SZ   128
#define P_SZ   435
#define BM     128
#define PCH    15                     // consecutive pairs per block
#define NCHUNK 29                     // 435 / 15
#define FD     (F_SZ * D_SZ)          // 3840
#define FEMB_ELEMS (B_SZ * F_SZ * D_SZ)
#define W_ELEMS    (P_SZ * D_SZ * D_SZ)
#define GRID_MAIN  (NCHUNK * 32)      // 928 = 8 * 116

typedef __bf16 bf16x8 __attribute__((ext_vector_type(8)));
typedef float  f32x4  __attribute__((ext_vector_type(4)));
typedef unsigned short u16x8 __attribute__((ext_vector_type(8)));
typedef unsigned short u16x4 __attribute__((ext_vector_type(4)));

__device__ __forceinline__ unsigned short f2bf(float x) {
    unsigned int u = __float_as_uint(x);
    u += 0x7fffu + ((u >> 16) & 1u);
    return (unsigned short)(u >> 16);
}
__device__ __forceinline__ float bf2f(unsigned short v) {
    return __uint_as_float(((unsigned int)v) << 16);
}
__device__ __forceinline__ void gl_lds16(const void* g, void* l) {
    __builtin_amdgcn_global_load_lds(
        (const __attribute__((address_space(1))) unsigned int*)g,
        (__attribute__((address_space(3))) unsigned int*)l, 16, 0, 0);
}
#define LGKM_BAR() do { \
    asm volatile("s_waitcnt lgkmcnt(0)" ::: "memory"); \
    __builtin_amdgcn_s_barrier(); } while (0)

__global__ __launch_bounds__(256)
void cvt_bf16_kernel(const float* __restrict__ src,
                     unsigned short* __restrict__ dst, int n8) {
    int stride = gridDim.x * blockDim.x;
    for (int i = blockIdx.x * blockDim.x + threadIdx.x; i < n8; i += stride) {
        const float* s = src + (size_t)i * 8;
        f32x4 a = *reinterpret_cast<const f32x4*>(s);
        f32x4 b = *reinterpret_cast<const f32x4*>(s + 4);
        u16x8 v;
        v[0]=f2bf(a[0]); v[1]=f2bf(a[1]); v[2]=f2bf(a[2]); v[3]=f2bf(a[3]);
        v[4]=f2bf(b[0]); v[5]=f2bf(b[1]); v[6]=f2bf(b[2]); v[7]=f2bf(b[3]);
        *reinterpret_cast<u16x8*>(dst + (size_t)i * 8) = v;
    }
}

// block = (b-tile 128 rows, 15 consecutive pairs), 512 thr / 8 waves.
// Epilogue: acc -> LDS scratch -> row-major readback, 512B-contiguous NT
// stores. vj prefetched to REGISTERS at step start so the store phases
// contain no loads -> no in-order-vmcnt waits on NT store retirement.
__global__ __launch_bounds__(512, 2)
void bilinear_kernel(const unsigned short* __restrict__ wsA,
                     const unsigned short* __restrict__ wsW,
                     float* __restrict__ out) {
    __shared__ unsigned short As[BM * D_SZ];     // 32 KB; scratch after prologue
    __shared__ unsigned short Ws[D_SZ * D_SZ];   // 32 KB
    float* scrf = reinterpret_cast<float*>(As);  // [64 rows][32 chunks16B] swz

    // XCD swizzle: each XCD owns a 4-btile group (vj slice 3.9 MB -> L2-fit)
    const int orig  = blockIdx.x;
    const int btgrp = orig & 7;
    const int idx   = orig >> 3;          // 0..115
    const int chunk = idx % NCHUNK;
    const int btsub = idx / NCHUNK;       // 0..3
    const int m0    = (btgrp * 4 + btsub) * BM;
    const int p0    = chunk * PCH;

    int fi = 0, rem = p0;
    while (rem >= F_SZ - 1 - fi) { rem -= F_SZ - 1 - fi; ++fi; }
    int fj = fi + 1 + rem;

    const int tid  = threadIdx.x;
    const int lane = tid & 63;
    const int wave = tid >> 6;      // 0..7
    const int l16  = lane >> 4;
    const int lc   = lane & 15;

    // readback geometry for this thread (fixed across steps)
    const int rb_r  = (tid * 16) >> 9;          // row 0..15 base (i adds 16/iter)
    const int rb_cb = ((tid * 16) >> 4) & 31;   // 16B chunk in row

    // ---- prologue: stage A(fi) + W(p0) via global_load_lds, swizzled src ----
    {
        const unsigned short* baseA = wsA + (size_t)m0 * FD + fi * D_SZ;
        #pragma unroll
        for (int it = 0; it < 4; ++it) {
            int r0 = it * 32 + wave * 4;
            int rl = r0 + l16;
            int cs = lc ^ (rl & 7);
            gl_lds16(baseA + (size_t)rl * FD + cs * 8, &As[r0 * 128]);
        }
        const unsigned short* baseW = wsW + (size_t)p0 * (D_SZ * D_SZ);
        #pragma unroll
        for (int it = 0; it < 4; ++it) {
            int r0 = it * 32 + wave * 4;
            int rl = r0 + l16;
            int cs = lc ^ (rl & 7);
            gl_lds16(baseW + rl * 128 + cs * 8, &Ws[r0 * 128]);
        }
    }
    __syncthreads();    // full drain once (gl_lds)

    const int wb = (wave & 3) * 32;    // b-range (32 rows) of this wave
    const int we = (wave >> 2) * 64;   // e-range (64) of this wave
    const int pass_sel = (wave & 3) >> 1;
    const int rbase    = (wave & 1) * 32;

    bf16x8 afr[2][4];
    #pragma unroll
    for (int m = 0; m < 2; ++m) {
        int bl = wb + m * 16 + lc;
        #pragma unroll
        for (int kk = 0; kk < 4; ++kk)
            afr[m][kk] = *reinterpret_cast<const bf16x8*>(
                &As[bl * 128 + (((kk * 4 + l16) ^ (bl & 7)) * 8)]);
    }

    for (int s = 0;;) {
        const int p = p0 + s;
        const bool has_next = (s + 1 < PCH);   // block-uniform

        // ---- prefetch: this step's vj (registers) + next step's W ----
        u16x4 vjreg[8];
        #pragma unroll
        for (int i = 0; i < 4; ++i) {
            int r  = rb_r + i * 16;
            const unsigned short* v0 =
                wsA + (size_t)(m0 + r) * FD + fj * D_SZ + rb_cb * 4;
            vjreg[i]     = *reinterpret_cast<const u16x4*>(v0);
            vjreg[4 + i] = *reinterpret_cast<const u16x4*>(v0 + (size_t)64 * FD);
        }

        int fi_n = fi, fj_n = fj;
        bool achg = false;
        u16x8 wreg[4];
        if (has_next) {
            const bool wrap = (fj == F_SZ - 1);
            fi_n = wrap ? fi + 1 : fi;
            fj_n = wrap ? fi + 2 : fj + 1;
            achg = wrap;
            const unsigned short* baseW = wsW + (size_t)(p + 1) * (D_SZ * D_SZ);
            #pragma unroll
            for (int it = 0; it < 4; ++it)
                wreg[it] = *reinterpret_cast<const u16x8*>(
                    baseW + (it * 512 + tid) * 8);
        }

        // ---- MFMA ----
        f32x4 acc[4][2];
        #pragma unroll
        for (int n = 0; n < 4; ++n)
            #pragma unroll
            for (int m = 0; m < 2; ++m) acc[n][m] = (f32x4)0.0f;

        #pragma unroll
        for (int n = 0; n < 4; ++n) {
            int el = we + n * 16 + lc;
            #pragma unroll
            for (int kk = 0; kk < 4; ++kk) {
                bf16x8 wfr = *reinterpret_cast<const bf16x8*>(
                    &Ws[el * 128 + (((kk * 4 + l16) ^ (el & 7)) * 8)]);
                #pragma unroll
                for (int m = 0; m < 2; ++m)
                    acc[n][m] = __builtin_amdgcn_mfma_f32_16x16x32_bf16(
                        wfr, afr[m][kk], acc[n][m], 0, 0, 0);
            }
        }

        LGKM_BAR();   // MFMA Ws/scr reads done everywhere

        // ---- phase B: restage next W; pass-0 waves dump acc to scratch ----
        if (has_next) {
            #pragma unroll
            for (int it = 0; it < 4; ++it) {
                int cl  = it * 512 + tid;
                int row = cl >> 4;
                int c   = cl & 15;
                *reinterpret_cast<u16x8*>(
                    &Ws[row * 128 + ((c ^ (row & 7)) * 8)]) = wreg[it];
            }
        }
        if (pass_sel == 0) {
            #pragma unroll
            for (int m = 0; m < 2; ++m) {
                int r = rbase + m * 16 + lc;
                #pragma unroll
                for (int n = 0; n < 4; ++n) {
                    int c = (we >> 2) + n * 4 + l16;
                    *reinterpret_cast<f32x4*>(
                        &scrf[(r * 32 + (c ^ (r & 7))) * 4]) = acc[n][m];
                }
            }
        }
        LGKM_BAR();

        // ---- phase C: readback pass 0 — LDS read + NT store ONLY ----
        #pragma unroll
        for (int i = 0; i < 4; ++i) {
            int r  = rb_r + i * 16;
            f32x4 v = *reinterpret_cast<const f32x4*>(
                &scrf[(r * 32 + (rb_cb ^ (r & 7))) * 4]);
            f32x4 o;
            o[0] = v[0] * bf2f(vjreg[i][0]);
            o[1] = v[1] * bf2f(vjreg[i][1]);
            o[2] = v[2] * bf2f(vjreg[i][2]);
            o[3] = v[3] * bf2f(vjreg[i][3]);
            __builtin_nontemporal_store(o, reinterpret_cast<f32x4*>(
                out + ((size_t)(m0 + r) * P_SZ + p) * D_SZ + rb_cb * 4));
        }
        LGKM_BAR();

        // ---- phase D: pass-1 waves dump acc ----
        if (pass_sel == 1) {
            #pragma unroll
            for (int m = 0; m < 2; ++m) {
                int r = rbase + m * 16 + lc;
                #pragma unroll
                for (int n = 0; n < 4; ++n) {
                    int c = (we >> 2) + n * 4 + l16;
                    *reinterpret_cast<f32x4*>(
                        &scrf[(r * 32 + (c ^ (r & 7))) * 4]) = acc[n][m];
                }
            }
        }
        LGKM_BAR();

        // ---- phase E: readback pass 1 ----
        #pragma unroll
        for (int i = 0; i < 4; ++i) {
            int r  = rb_r + i * 16;
            f32x4 v = *reinterpret_cast<const f32x4*>(
                &scrf[(r * 32 + (rb_cb ^ (r & 7))) * 4]);
            f32x4 o;
            o[0] = v[0] * bf2f(vjreg[4 + i][0]);
            o[1] = v[1] * bf2f(vjreg[4 + i][1]);
            o[2] = v[2] * bf2f(vjreg[4 + i][2]);
            o[3] = v[3] * bf2f(vjreg[4 + i][3]);
            __builtin_nontemporal_store(o, reinterpret_cast<f32x4*>(
                out + ((size_t)(m0 + 64 + r) * P_SZ + p) * D_SZ + rb_cb * 4));
        }

        if (!has_next) break;

        // ---- A-fragment reload straight from global on fi change ----
        if (achg) {
            #pragma unroll
            for (int m = 0; m < 2; ++m) {
                const unsigned short* ar =
                    wsA + (size_t)(m0 + wb + m * 16 + lc) * FD + fi_n * D_SZ;
                #pragma unroll
                for (int kk = 0; kk < 4; ++kk)
                    afr[m][kk] = *reinterpret_cast<const bf16x8*>(
                        ar + (kk * 4 + l16) * 8);
            }
        }
        fi = fi_n; fj = fj_n; ++s;
    }
}

extern "C" void kernel_launch(void* const* d_in, const int* in_sizes, int n_in,
                              void* d_out, int out_size, void* d_ws, size_t ws_size,
                              hipStream_t stream) {
    const float* femb = (const float*)d_in[0];
    const float* W    = (const float*)d_in[1];
    float* out        = (float*)d_out;

    unsigned short* wsA = (unsigned short*)d_ws;
    unsigned short* wsW = wsA + FEMB_ELEMS;

    hipLaunchKernelGGL(cvt_bf16_kernel, dim3(2048), dim3(256), 0, stream,
                       femb, wsA, FEMB_ELEMS / 8);
    hipLaunchKernelGGL(cvt_bf16_kernel, dim3(2048), dim3(256), 0, stream,
                       W, wsW, W_ELEMS / 8);
    hipLaunchKernelGGL(bilinear_kernel, dim3(GRID_MAIN), dim3(512), 0, stream,
                       wsA, wsW, out);
}